// Round 1
// baseline (335.637 us; speedup 1.0000x reference)
//
#include <hip/hip_runtime.h>

// Problem constants (from reference)
constexpr int   NBX        = 128;
constexpr int   NBY        = 128;
constexpr float SX         = 7.8125f;   // (1000-0)/128, exact in fp32
constexpr float SY         = 7.8125f;
constexpr int   NUM_NETS   = 100000;
constexpr int   NUM_NODES  = 200000;
constexpr int   NUM_MOVABLE= 180000;
constexpr int   NUM_PINS   = 400000;
constexpr float UNIT_H_CAP = 1.5f;
constexpr float UNIT_V_CAP = 1.4f;
constexpr int   DDIM       = 130;       // diff-array dim (writes land at idx <= 129)

__device__ __forceinline__ float edgef(int t, float S) { return (float)t * S; }

// exact bin index: edge(a) <= v < edge(a+1)
__device__ __forceinline__ int bin_of(float v, float S) {
    int t = (int)floorf(v / S);
    while (edgef(t + 1, S) <= v) ++t;
    while (edgef(t, S)     >  v) --t;
    return t;
}

__device__ __forceinline__ float phi(int t, float lo, float hi, float S) {
    return fminf(fmaxf(edgef(t, S), lo), hi);
}

// second difference of clamp ramp: delta-of-overlap vector, <=4 nonzeros
__device__ __forceinline__ int second_diff(float lo, float hi, float S,
                                           int* idx, float* val) {
    int a = bin_of(lo, S);
    int b = bin_of(hi, S);
    int n = 0;
    idx[n] = a;
    val[n] = phi(a + 1, lo, hi, S) - 2.f * phi(a, lo, hi, S) + phi(a - 1, lo, hi, S);
    ++n;
    idx[n] = a + 1;
    val[n] = phi(a + 2, lo, hi, S) - 2.f * phi(a + 1, lo, hi, S) + phi(a, lo, hi, S);
    ++n;
    if (b > a + 1) {
        idx[n] = b;
        val[n] = phi(b + 1, lo, hi, S) - 2.f * phi(b, lo, hi, S) + phi(b - 1, lo, hi, S);
        ++n;
    }
    if (b > a) {
        idx[n] = b + 1;
        val[n] = phi(b + 2, lo, hi, S) - 2.f * phi(b + 1, lo, hi, S) + phi(b, lo, hi, S);
        ++n;
    }
    return n;
}

// Kernel 1: per-net bbox + scatter 2D-difference of cx*f(x)ox(y) outer products
__global__ __launch_bounds__(256) void net_diff_kernel(
    const float* __restrict__ pin_pos,
    const float* __restrict__ net_weights,
    const int*   __restrict__ netpin_start,
    const int*   __restrict__ flat_netpin,
    float* __restrict__ Dx, float* __restrict__ Dy) {
    int n = blockIdx.x * blockDim.x + threadIdx.x;
    if (n >= NUM_NETS) return;
    int s = netpin_start[n];
    int e = netpin_start[n + 1];
    if (e <= s) return;
    float xmin = 1e30f, xmax = -1e30f, ymin = 1e30f, ymax = -1e30f;
    for (int p = s; p < e; ++p) {
        int pin = flat_netpin[p];
        float px = pin_pos[pin];
        float py = pin_pos[pin + NUM_PINS];
        xmin = fminf(xmin, px); xmax = fmaxf(xmax, px);
        ymin = fminf(ymin, py); ymax = fmaxf(ymax, py);
    }
    float w  = net_weights[n];
    float dx = xmax - xmin;
    float dy = ymax - ymin;
    float cx = (dy > 0.f) ? (w / dy) : 0.f;   // scales map_x
    float cy = (dx > 0.f) ? (w / dx) : 0.f;   // scales map_y
    if (cx == 0.f && cy == 0.f) return;

    int   ixs[4]; float vxs[4];
    int   iys[4]; float vys[4];
    int nx = second_diff(xmin, xmax, SX, ixs, vxs);
    int ny = second_diff(ymin, ymax, SY, iys, vys);

    for (int i = 0; i < nx; ++i) {
        float fi = vxs[i];
        if (fi == 0.f) continue;
        int row = ixs[i];
        if (row < 0 || row >= DDIM) continue;
        for (int j = 0; j < ny; ++j) {
            float t = fi * vys[j];
            if (t == 0.f) continue;
            int col = iys[j];
            if (col < 0 || col >= DDIM) continue;
            int off = row * DDIM + col;
            if (cx != 0.f) atomicAdd(Dx + off, cx * t);
            if (cy != 0.f) atomicAdd(Dy + off, cy * t);
        }
    }
}

// Kernel 2: 2D inclusive prefix-sum of both diff arrays -> util map (fused clip)
__global__ __launch_bounds__(128) void util_kernel(
    float* __restrict__ Dx, float* __restrict__ Dy, float* __restrict__ util) {
    int t = threadIdx.x;
    if (t < NBX) {  // prefix over rows (x-direction), one thread per column j=t
        float rx = 0.f, ry = 0.f;
        for (int i = 0; i < NBX; ++i) {
            rx += Dx[i * DDIM + t]; Dx[i * DDIM + t] = rx;
            ry += Dy[i * DDIM + t]; Dy[i * DDIM + t] = ry;
        }
    }
    __syncthreads();
    if (t < NBX) {  // prefix over columns (y-direction), one thread per row i=t
        const float invx = 1.f / (SX * SY * UNIT_H_CAP);
        const float invy = 1.f / (SX * SY * UNIT_V_CAP);
        float rx = 0.f, ry = 0.f;
        for (int j = 0; j < NBY; ++j) {
            rx += Dx[t * DDIM + j];
            ry += Dy[t * DDIM + j];
            float u = fmaxf(rx * invx, ry * invy);
            util[t * NBY + j] = fminf(fmaxf(u, 0.5f), 2.0f);
        }
    }
}

// Kernel 3: per-movable-node area = sum_{x,y} ox(x)*util(x,y)*oy(y); <=3x3 bins
__global__ __launch_bounds__(256) void node_kernel(
    const float* __restrict__ pos,
    const float* __restrict__ nsx,
    const float* __restrict__ nsy,
    const float* __restrict__ util,
    float* __restrict__ out) {
    int m = blockIdx.x * blockDim.x + threadIdx.x;
    if (m >= NUM_MOVABLE) return;
    float x  = pos[m];
    float y  = pos[NUM_NODES + m];
    float xh = x + nsx[m];
    float yh = y + nsy[m];
    int ax = max(0,   (int)floorf(x  / SX) - 1);
    int bx = min(127, (int)floorf(xh / SX) + 1);
    int ay = max(0,   (int)floorf(y  / SY) - 1);
    int by = min(127, (int)floorf(yh / SY) + 1);
    float acc = 0.f;
    for (int i = ax; i <= bx; ++i) {
        float ov = fminf(edgef(i + 1, SX), xh) - fmaxf(edgef(i, SX), x);
        if (ov <= 0.f) continue;
        float inner = 0.f;
        for (int j = ay; j <= by; ++j) {
            float ovy = fminf(edgef(j + 1, SY), yh) - fmaxf(edgef(j, SY), y);
            if (ovy > 0.f) inner += ovy * util[i * NBY + j];
        }
        acc += ov * inner;
    }
    out[m] = acc;
}

extern "C" void kernel_launch(void* const* d_in, const int* in_sizes, int n_in,
                              void* d_out, int out_size, void* d_ws, size_t ws_size,
                              hipStream_t stream) {
    const float* pos      = (const float*)d_in[0];
    const float* pin_pos  = (const float*)d_in[1];
    const float* nsx      = (const float*)d_in[2];
    const float* nsy      = (const float*)d_in[3];
    const float* nw       = (const float*)d_in[4];
    const int*   npstart  = (const int*)d_in[5];
    const int*   fnp      = (const int*)d_in[6];
    float*       out      = (float*)d_out;

    float* Dx   = (float*)d_ws;
    float* Dy   = Dx + DDIM * DDIM;
    float* util = Dy + DDIM * DDIM;

    // zero the two diff arrays (ws is poisoned 0xAA before every launch)
    hipMemsetAsync(d_ws, 0, (size_t)(2 * DDIM * DDIM) * sizeof(float), stream);

    net_diff_kernel<<<(NUM_NETS + 255) / 256, 256, 0, stream>>>(
        pin_pos, nw, npstart, fnp, Dx, Dy);
    util_kernel<<<1, 128, 0, stream>>>(Dx, Dy, util);
    node_kernel<<<(NUM_MOVABLE + 255) / 256, 256, 0, stream>>>(
        pos, nsx, nsy, util, out);
}

// Round 2
// 189.264 us; speedup vs baseline: 1.7734x; 1.7734x over previous
//
#include <hip/hip_runtime.h>

// Problem constants (from reference)
constexpr int   NB         = 128;          // bins per axis
constexpr int   NCELL      = NB * NB;      // 16384 cells = 64 KB fp32
constexpr float S          = 7.8125f;      // 1000/128, exact in fp32
constexpr int   NUM_NETS   = 100000;
constexpr int   NUM_NODES  = 200000;
constexpr int   NUM_MOVABLE= 180000;
constexpr int   NUM_PINS   = 400000;
constexpr float UNIT_H_CAP = 1.5f;
constexpr float UNIT_V_CAP = 1.4f;

#define TPB  256
#define MAXN 8   // max cached nets per thread (B*TPB*MAXN >= NUM_NETS for B>=49)

__device__ __forceinline__ float edgef(int t) { return (float)t * S; }

// exact bin index: edge(a) <= v < edge(a+1)
__device__ __forceinline__ int bin_of(float v) {
    int t = (int)floorf(v / S);
    while (edgef(t + 1) <= v) ++t;
    while (edgef(t)     >  v) --t;
    return t;
}

__device__ __forceinline__ float phi(int t, float lo, float hi) {
    return fminf(fmaxf(edgef(t), lo), hi);
}

// second difference of the clamp-ramp: <=4 nonzeros; indices >=128 never
// influence bins 0..127 and are dropped by the caller.
__device__ __forceinline__ int second_diff(float lo, float hi,
                                           int* idx, float* val) {
    int a = bin_of(lo);
    int b = bin_of(hi);
    int n = 0;
    idx[n] = a;
    val[n] = phi(a + 1, lo, hi) - 2.f * phi(a, lo, hi) + phi(a - 1, lo, hi);
    ++n;
    idx[n] = a + 1;
    val[n] = phi(a + 2, lo, hi) - 2.f * phi(a + 1, lo, hi) + phi(a, lo, hi);
    ++n;
    if (b > a + 1) {
        idx[n] = b;
        val[n] = phi(b + 1, lo, hi) - 2.f * phi(b, lo, hi) + phi(b - 1, lo, hi);
        ++n;
    }
    if (b > a) {
        idx[n] = b + 1;
        val[n] = phi(b + 2, lo, hi) - 2.f * phi(b + 1, lo, hi) + phi(b, lo, hi);
        ++n;
    }
    return n;
}

__device__ __forceinline__ void gather_bbox(
    const float* __restrict__ pin_pos, const int* __restrict__ nps,
    const int* __restrict__ fnp, int n,
    float& xmin, float& xmax, float& ymin, float& ymax) {
    int s = nps[n], e = nps[n + 1];
    xmin = 1e30f; xmax = -1e30f; ymin = 1e30f; ymax = -1e30f;
    for (int p = s; p < e; ++p) {
        int pin = fnp[p];
        float px = pin_pos[pin];
        float py = pin_pos[pin + NUM_PINS];
        xmin = fminf(xmin, px); xmax = fmaxf(xmax, px);
        ymin = fminf(ymin, py); ymax = fmaxf(ymax, py);
    }
}

// Kernel 1: per-block LDS-private 2D diff accumulation, two phases (x-map,
// y-map), bbox cached in registers between phases. No global atomics.
__global__ __launch_bounds__(TPB) void net_diff_kernel(
    const float* __restrict__ pin_pos,
    const float* __restrict__ net_weights,
    const int*   __restrict__ nps,
    const int*   __restrict__ fnp,
    float* __restrict__ Px, float* __restrict__ Py) {
    __shared__ float D[NCELL];   // 64 KB private diff array
    const int tid = threadIdx.x;
    const int gid = blockIdx.x * TPB + tid;
    const int T   = gridDim.x * TPB;

    for (int i = tid; i < NCELL; i += TPB) D[i] = 0.f;
    __syncthreads();

    float cxm[MAXN], cxM[MAXN], cym[MAXN], cyM[MAXN], cw[MAXN];

    for (int phase = 0; phase < 2; ++phase) {
        int k = 0;
        for (int n = gid; n < NUM_NETS; n += T, ++k) {
            float xmin, xmax, ymin, ymax, w;
            if (phase == 0) {
                gather_bbox(pin_pos, nps, fnp, n, xmin, xmax, ymin, ymax);
                w = net_weights[n];
                if (k < MAXN) { cxm[k]=xmin; cxM[k]=xmax; cym[k]=ymin; cyM[k]=ymax; cw[k]=w; }
            } else if (k < MAXN) {
                xmin=cxm[k]; xmax=cxM[k]; ymin=cym[k]; ymax=cyM[k]; w=cw[k];
            } else {
                gather_bbox(pin_pos, nps, fnp, n, xmin, xmax, ymin, ymax);
                w = net_weights[n];
            }
            float dx = xmax - xmin, dy = ymax - ymin;
            float c = (phase == 0) ? ((dy > 0.f) ? w / dy : 0.f)
                                   : ((dx > 0.f) ? w / dx : 0.f);
            if (c == 0.f) continue;
            int ixs[4]; float vxs[4]; int iys[4]; float vys[4];
            int nx = second_diff(xmin, xmax, ixs, vxs);
            int ny = second_diff(ymin, ymax, iys, vys);
            for (int i = 0; i < nx; ++i) {
                int row = ixs[i];
                float fi = vxs[i];
                if (fi == 0.f || row < 0 || row >= NB) continue;
                for (int j = 0; j < ny; ++j) {
                    int col = iys[j];
                    float t = fi * vys[j];
                    if (t == 0.f || col < 0 || col >= NB) continue;
                    atomicAdd(&D[row * NB + col], c * t);
                }
            }
        }
        __syncthreads();
        float* P = (phase == 0 ? Px : Py) + (size_t)blockIdx.x * NCELL;
        for (int i = tid; i < NCELL; i += TPB) { P[i] = D[i]; D[i] = 0.f; }
        __syncthreads();
    }
}

// Kernel 2: sum the B per-block partials -> final Dx, Dy
__global__ __launch_bounds__(256) void reduce_kernel(
    const float* __restrict__ Px, const float* __restrict__ Py,
    float* __restrict__ Dx, float* __restrict__ Dy, int B) {
    int c = blockIdx.x * blockDim.x + threadIdx.x;
    if (c >= 2 * NCELL) return;
    const float* P = (c < NCELL) ? Px : Py;
    float*       D = (c < NCELL) ? Dx : Dy;
    int cell = c & (NCELL - 1);
    float acc = 0.f;
    for (int b = 0; b < B; ++b) acc += P[(size_t)b * NCELL + cell];
    D[cell] = acc;
}

// Kernel 3: 2D prefix of both diff arrays -> clipped util map
__global__ __launch_bounds__(NB) void util_kernel(
    float* __restrict__ Dx, float* __restrict__ Dy, float* __restrict__ util) {
    int t = threadIdx.x;
    float rx = 0.f, ry = 0.f;
    #pragma unroll 4
    for (int i = 0; i < NB; ++i) {
        rx += Dx[i * NB + t]; Dx[i * NB + t] = rx;
        ry += Dy[i * NB + t]; Dy[i * NB + t] = ry;
    }
    __syncthreads();
    const float invx = 1.f / (S * S * UNIT_H_CAP);
    const float invy = 1.f / (S * S * UNIT_V_CAP);
    rx = 0.f; ry = 0.f;
    #pragma unroll 4
    for (int j = 0; j < NB; ++j) {
        rx += Dx[t * NB + j];
        ry += Dy[t * NB + j];
        float u = fmaxf(rx * invx, ry * invy);
        util[t * NB + j] = fminf(fmaxf(u, 0.5f), 2.0f);
    }
}

// Kernel 4: per-movable-node area = ox^T * util * oy (<=3x3 bins per node)
__global__ __launch_bounds__(256) void node_kernel(
    const float* __restrict__ pos,
    const float* __restrict__ nsx,
    const float* __restrict__ nsy,
    const float* __restrict__ util,
    float* __restrict__ out) {
    int m = blockIdx.x * blockDim.x + threadIdx.x;
    if (m >= NUM_MOVABLE) return;
    float x  = pos[m];
    float y  = pos[NUM_NODES + m];
    float xh = x + nsx[m];
    float yh = y + nsy[m];
    int ax = max(0,      (int)floorf(x  / S) - 1);
    int bx = min(NB - 1, (int)floorf(xh / S) + 1);
    int ay = max(0,      (int)floorf(y  / S) - 1);
    int by = min(NB - 1, (int)floorf(yh / S) + 1);
    float acc = 0.f;
    for (int i = ax; i <= bx; ++i) {
        float ov = fminf(edgef(i + 1), xh) - fmaxf(edgef(i), x);
        if (ov <= 0.f) continue;
        float inner = 0.f;
        for (int j = ay; j <= by; ++j) {
            float ovy = fminf(edgef(j + 1), yh) - fmaxf(edgef(j), y);
            if (ovy > 0.f) inner += ovy * util[i * NB + j];
        }
        acc += ov * inner;
    }
    out[m] = acc;
}

extern "C" void kernel_launch(void* const* d_in, const int* in_sizes, int n_in,
                              void* d_out, int out_size, void* d_ws, size_t ws_size,
                              hipStream_t stream) {
    const float* pos      = (const float*)d_in[0];
    const float* pin_pos  = (const float*)d_in[1];
    const float* nsx      = (const float*)d_in[2];
    const float* nsy      = (const float*)d_in[3];
    const float* nw       = (const float*)d_in[4];
    const int*   npstart  = (const int*)d_in[5];
    const int*   fnp      = (const int*)d_in[6];
    float*       out      = (float*)d_out;

    // ws layout: [Dx 16384][Dy 16384][util 16384][Px B*16384][Py B*16384]
    float* Dx   = (float*)d_ws;
    float* Dy   = Dx + NCELL;
    float* util = Dy + NCELL;
    float* Px   = util + NCELL;

    size_t fixed = (size_t)3 * NCELL * sizeof(float);
    int B = 128;
    if (ws_size > fixed) {
        size_t fit = (ws_size - fixed) / ((size_t)2 * NCELL * sizeof(float));
        if ((size_t)B > fit) B = (int)fit;
    } else {
        B = 1;
    }
    if (B < 1) B = 1;
    float* Py = Px + (size_t)B * NCELL;

    net_diff_kernel<<<B, TPB, 0, stream>>>(pin_pos, nw, npstart, fnp, Px, Py);
    reduce_kernel<<<(2 * NCELL + 255) / 256, 256, 0, stream>>>(Px, Py, Dx, Dy, B);
    util_kernel<<<1, NB, 0, stream>>>(Dx, Dy, util);
    node_kernel<<<(NUM_MOVABLE + 255) / 256, 256, 0, stream>>>(
        pos, nsx, nsy, util, out);
}

// Round 3
// 189.002 us; speedup vs baseline: 1.7758x; 1.0014x over previous
//
#include <hip/hip_runtime.h>

// Problem constants (from reference)
constexpr int   NB         = 128;          // bins per axis
constexpr int   NCELL      = NB * NB;      // 16384 cells = 64 KB fp32
constexpr float S          = 7.8125f;      // 1000/128, exact in fp32
constexpr int   NUM_NETS   = 100000;
constexpr int   NUM_NODES  = 200000;
constexpr int   NUM_MOVABLE= 180000;
constexpr int   NUM_PINS   = 400000;
constexpr float UNIT_H_CAP = 1.5f;
constexpr float UNIT_V_CAP = 1.4f;

#define TPB   256
#define NDB   64    // blocks for net_diff (partials)

__device__ __forceinline__ float edgef(int t) { return (float)t * S; }

// exact bin index: edge(a) <= v < edge(a+1)
__device__ __forceinline__ int bin_of(float v) {
    int t = (int)floorf(v / S);
    while (edgef(t + 1) <= v) ++t;
    while (edgef(t)     >  v) --t;
    return t;
}

__device__ __forceinline__ float phi(int t, float lo, float hi) {
    return fminf(fmaxf(edgef(t), lo), hi);
}

// second difference of the clamp-ramp: <=4 nonzeros; indices >=128 never
// influence bins 0..127 and are dropped by the caller.
__device__ __forceinline__ int second_diff(float lo, float hi,
                                           int* idx, float* val) {
    int a = bin_of(lo);
    int b = bin_of(hi);
    int n = 0;
    idx[n] = a;
    val[n] = phi(a + 1, lo, hi) - 2.f * phi(a, lo, hi) + phi(a - 1, lo, hi);
    ++n;
    idx[n] = a + 1;
    val[n] = phi(a + 2, lo, hi) - 2.f * phi(a + 1, lo, hi) + phi(a, lo, hi);
    ++n;
    if (b > a + 1) {
        idx[n] = b;
        val[n] = phi(b + 1, lo, hi) - 2.f * phi(b, lo, hi) + phi(b - 1, lo, hi);
        ++n;
    }
    if (b > a) {
        idx[n] = b + 1;
        val[n] = phi(b + 2, lo, hi) - 2.f * phi(b + 1, lo, hi) + phi(b, lo, hi);
        ++n;
    }
    return n;
}

// K1: per-net bbox + coefficients, full-occupancy gather kernel.
// bb[n] = {xmin, xmax, ymin, ymax}, cc[n] = {cx, cy}
__global__ __launch_bounds__(TPB) void bbox_kernel(
    const float* __restrict__ pin_pos,
    const float* __restrict__ net_weights,
    const int*   __restrict__ nps,
    const int*   __restrict__ fnp,
    float4* __restrict__ bb, float2* __restrict__ cc) {
    int n = blockIdx.x * TPB + threadIdx.x;
    if (n >= NUM_NETS) return;
    int s = nps[n], e = nps[n + 1];
    float xmin = 1e30f, xmax = -1e30f, ymin = 1e30f, ymax = -1e30f;
    for (int p = s; p < e; ++p) {
        int pin = fnp[p];
        float px = pin_pos[pin];
        float py = pin_pos[pin + NUM_PINS];
        xmin = fminf(xmin, px); xmax = fmaxf(xmax, px);
        ymin = fminf(ymin, py); ymax = fmaxf(ymax, py);
    }
    float w  = (e > s) ? net_weights[n] : 0.f;
    float dx = xmax - xmin, dy = ymax - ymin;
    float cx = (e > s && dy > 0.f) ? w / dy : 0.f;
    float cy = (e > s && dx > 0.f) ? w / dx : 0.f;
    bb[n] = make_float4(xmin, xmax, ymin, ymax);
    cc[n] = make_float2(cx, cy);
}

// K2: per-block LDS-private 2D diff accumulation; two phases (x-map, y-map).
__global__ __launch_bounds__(TPB) void net_diff_kernel(
    const float4* __restrict__ bb,
    const float2* __restrict__ cc,
    float* __restrict__ Px, float* __restrict__ Py) {
    __shared__ float D[NCELL];   // 64 KB private diff array
    const int tid = threadIdx.x;
    const int gid = blockIdx.x * TPB + tid;
    const int T   = gridDim.x * TPB;

    for (int i = tid; i < NCELL; i += TPB) D[i] = 0.f;
    __syncthreads();

    for (int phase = 0; phase < 2; ++phase) {
        for (int n = gid; n < NUM_NETS; n += T) {
            float4 b = bb[n];
            float2 c2 = cc[n];
            float c = (phase == 0) ? c2.x : c2.y;
            if (c == 0.f) continue;
            int ixs[4]; float vxs[4]; int iys[4]; float vys[4];
            int nx = second_diff(b.x, b.y, ixs, vxs);
            int ny = second_diff(b.z, b.w, iys, vys);
            for (int i = 0; i < nx; ++i) {
                int row = ixs[i];
                float fi = vxs[i];
                if (fi == 0.f || row < 0 || row >= NB) continue;
                for (int j = 0; j < ny; ++j) {
                    int col = iys[j];
                    float t = fi * vys[j];
                    if (t == 0.f || col < 0 || col >= NB) continue;
                    atomicAdd(&D[row * NB + col], c * t);
                }
            }
        }
        __syncthreads();
        float* P = (phase == 0 ? Px : Py) + (size_t)blockIdx.x * NCELL;
        for (int i = tid; i < NCELL; i += TPB) { P[i] = D[i]; D[i] = 0.f; }
        __syncthreads();
    }
}

// K3: sum the B per-block partials -> Dx, Dy. float4 + 4 independent chains.
__global__ __launch_bounds__(256) void reduce_kernel(
    const float4* __restrict__ Px, const float4* __restrict__ Py,
    float4* __restrict__ Dx, float4* __restrict__ Dy, int B) {
    constexpr int NC4 = NCELL / 4;
    int t = blockIdx.x * blockDim.x + threadIdx.x;
    if (t >= 2 * NC4) return;
    const float4* P = (t < NC4) ? Px : Py;
    float4*       D = (t < NC4) ? Dx : Dy;
    int c4 = t & (NC4 - 1);
    float4 a0 = {0,0,0,0}, a1 = {0,0,0,0}, a2 = {0,0,0,0}, a3 = {0,0,0,0};
    int b = 0;
    for (; b + 3 < B; b += 4) {
        float4 v0 = P[(size_t)(b    ) * NC4 + c4];
        float4 v1 = P[(size_t)(b + 1) * NC4 + c4];
        float4 v2 = P[(size_t)(b + 2) * NC4 + c4];
        float4 v3 = P[(size_t)(b + 3) * NC4 + c4];
        a0.x += v0.x; a0.y += v0.y; a0.z += v0.z; a0.w += v0.w;
        a1.x += v1.x; a1.y += v1.y; a1.z += v1.z; a1.w += v1.w;
        a2.x += v2.x; a2.y += v2.y; a2.z += v2.z; a2.w += v2.w;
        a3.x += v3.x; a3.y += v3.y; a3.z += v3.z; a3.w += v3.w;
    }
    for (; b < B; ++b) {
        float4 v = P[(size_t)b * NC4 + c4];
        a0.x += v.x; a0.y += v.y; a0.z += v.z; a0.w += v.w;
    }
    float4 r;
    r.x = (a0.x + a1.x) + (a2.x + a3.x);
    r.y = (a0.y + a1.y) + (a2.y + a3.y);
    r.z = (a0.z + a1.z) + (a2.z + a3.z);
    r.w = (a0.w + a1.w) + (a2.w + a3.w);
    D[c4] = r;
}

// K4a: prefix along x (down columns). t<128 -> Dx col t; else Dy col t-128.
__global__ __launch_bounds__(256) void prefix_x_kernel(
    const float* __restrict__ Dx, const float* __restrict__ Dy,
    float* __restrict__ Xpx, float* __restrict__ Xpy) {
    int t = threadIdx.x;
    const float* D = (t < NB) ? Dx : Dy;
    float*       O = (t < NB) ? Xpx : Xpy;
    int col = t & (NB - 1);
    float acc = 0.f;
    #pragma unroll
    for (int i = 0; i < NB; ++i) {
        acc += D[i * NB + col];
        O[i * NB + col] = acc;
    }
}

// K4b: prefix along y (along rows) -> final map_x / map_y (2D prefix sums).
__global__ __launch_bounds__(256) void prefix_y_kernel(
    const float* __restrict__ Xpx, const float* __restrict__ Xpy,
    float* __restrict__ Mx, float* __restrict__ My) {
    int t = threadIdx.x;
    const float* I = (t < NB) ? Xpx : Xpy;
    float*       O = (t < NB) ? Mx : My;
    int row = t & (NB - 1);
    float acc = 0.f;
    #pragma unroll
    for (int j = 0; j < NB; ++j) {
        acc += I[row * NB + j];
        O[row * NB + j] = acc;
    }
}

// K5: per-movable-node area = sum over <=3x3 bins of ox*clip(max(ux,uy))*oy
__global__ __launch_bounds__(256) void node_kernel(
    const float* __restrict__ pos,
    const float* __restrict__ nsx,
    const float* __restrict__ nsy,
    const float* __restrict__ Mx,
    const float* __restrict__ My,
    float* __restrict__ out) {
    constexpr float invx = 1.f / (S * S * UNIT_H_CAP);
    constexpr float invy = 1.f / (S * S * UNIT_V_CAP);
    int m = blockIdx.x * blockDim.x + threadIdx.x;
    if (m >= NUM_MOVABLE) return;
    float x  = pos[m];
    float y  = pos[NUM_NODES + m];
    float xh = x + nsx[m];
    float yh = y + nsy[m];
    int ax = max(0,      (int)floorf(x  / S) - 1);
    int bx = min(NB - 1, (int)floorf(xh / S) + 1);
    int ay = max(0,      (int)floorf(y  / S) - 1);
    int by = min(NB - 1, (int)floorf(yh / S) + 1);
    float acc = 0.f;
    for (int i = ax; i <= bx; ++i) {
        float ov = fminf(edgef(i + 1), xh) - fmaxf(edgef(i), x);
        if (ov <= 0.f) continue;
        float inner = 0.f;
        for (int j = ay; j <= by; ++j) {
            float ovy = fminf(edgef(j + 1), yh) - fmaxf(edgef(j), y);
            if (ovy > 0.f) {
                float u = fmaxf(Mx[i * NB + j] * invx, My[i * NB + j] * invy);
                u = fminf(fmaxf(u, 0.5f), 2.0f);
                inner += ovy * u;
            }
        }
        acc += ov * inner;
    }
    out[m] = acc;
}

extern "C" void kernel_launch(void* const* d_in, const int* in_sizes, int n_in,
                              void* d_out, int out_size, void* d_ws, size_t ws_size,
                              hipStream_t stream) {
    const float* pos      = (const float*)d_in[0];
    const float* pin_pos  = (const float*)d_in[1];
    const float* nsx      = (const float*)d_in[2];
    const float* nsy      = (const float*)d_in[3];
    const float* nw       = (const float*)d_in[4];
    const int*   npstart  = (const int*)d_in[5];
    const int*   fnp      = (const int*)d_in[6];
    float*       out      = (float*)d_out;

    // ws layout (floats):
    // bb[4*NETS] cc[2*NETS] Dx Dy Xpx Xpy Mx My [Px B*NCELL] [Py B*NCELL]
    float* w    = (float*)d_ws;
    float4* bb  = (float4*)w;              w += 4 * NUM_NETS;
    float2* cc  = (float2*)w;              w += 2 * NUM_NETS;
    float* Dx   = w;                       w += NCELL;
    float* Dy   = w;                       w += NCELL;
    float* Xpx  = w;                       w += NCELL;
    float* Xpy  = w;                       w += NCELL;
    float* Mx   = w;                       w += NCELL;
    float* My   = w;                       w += NCELL;
    float* Px   = w;

    size_t fixed = (size_t)(6 * NUM_NETS + 6 * NCELL) * sizeof(float);
    int B = NDB;
    if (ws_size > fixed) {
        size_t fit = (ws_size - fixed) / ((size_t)2 * NCELL * sizeof(float));
        if ((size_t)B > fit) B = (int)fit;
    } else {
        B = 1;
    }
    if (B < 1) B = 1;
    float* Py = Px + (size_t)B * NCELL;

    bbox_kernel<<<(NUM_NETS + TPB - 1) / TPB, TPB, 0, stream>>>(
        pin_pos, nw, npstart, fnp, bb, cc);
    net_diff_kernel<<<B, TPB, 0, stream>>>(bb, cc, Px, Py);
    reduce_kernel<<<(2 * (NCELL / 4) + 255) / 256, 256, 0, stream>>>(
        (const float4*)Px, (const float4*)Py, (float4*)Dx, (float4*)Dy, B);
    prefix_x_kernel<<<1, 256, 0, stream>>>(Dx, Dy, Xpx, Xpy);
    prefix_y_kernel<<<1, 256, 0, stream>>>(Xpx, Xpy, Mx, My);
    node_kernel<<<(NUM_MOVABLE + 255) / 256, 256, 0, stream>>>(
        pos, nsx, nsy, Mx, My, out);
}

// Round 4
// 147.297 us; speedup vs baseline: 2.2786x; 1.2831x over previous
//
#include <hip/hip_runtime.h>

// Problem constants (from reference)
constexpr int   NB         = 128;          // bins per axis
constexpr int   NCELL      = NB * NB;      // 16384 cells = 64 KB fp32
constexpr float S          = 7.8125f;      // 1000/128, exact in fp32
constexpr int   NUM_NETS   = 100000;
constexpr int   NUM_NODES  = 200000;
constexpr int   NUM_MOVABLE= 180000;
constexpr int   NUM_PINS   = 400000;
constexpr float UNIT_H_CAP = 1.5f;
constexpr float UNIT_V_CAP = 1.4f;

#define TPB    256
#define NDB    256   // blocks for net_diff: 1/CU -> LDS atomics spread over all CUs
#define NCHUNK 4     // b-parallelism in reduce

__device__ __forceinline__ float edgef(int t) { return (float)t * S; }

// exact bin index: edge(a) <= v < edge(a+1)
__device__ __forceinline__ int bin_of(float v) {
    int t = (int)floorf(v / S);
    while (edgef(t + 1) <= v) ++t;
    while (edgef(t)     >  v) --t;
    return t;
}

__device__ __forceinline__ float phi(int t, float lo, float hi) {
    return fminf(fmaxf(edgef(t), lo), hi);
}

// second difference of the clamp-ramp: <=4 nonzeros (indices >=128 are dropped
// by the caller; they never influence bins 0..127).
__device__ __forceinline__ int second_diff(float lo, float hi,
                                           int* idx, float* val) {
    int a = bin_of(lo);
    int b = bin_of(hi);
    int n = 0;
    idx[n] = a;
    val[n] = phi(a + 1, lo, hi) - 2.f * phi(a, lo, hi) + phi(a - 1, lo, hi);
    ++n;
    idx[n] = a + 1;
    val[n] = phi(a + 2, lo, hi) - 2.f * phi(a + 1, lo, hi) + phi(a, lo, hi);
    ++n;
    if (b > a + 1) {
        idx[n] = b;
        val[n] = phi(b + 1, lo, hi) - 2.f * phi(b, lo, hi) + phi(b - 1, lo, hi);
        ++n;
    }
    if (b > a) {
        idx[n] = b + 1;
        val[n] = phi(b + 2, lo, hi) - 2.f * phi(b + 1, lo, hi) + phi(b, lo, hi);
        ++n;
    }
    return n;
}

// K1: per-net bbox + coefficients. Fast path: 4 pins, 16B-aligned -> int4.
__global__ __launch_bounds__(TPB) void bbox_kernel(
    const float* __restrict__ pin_pos,
    const float* __restrict__ net_weights,
    const int*   __restrict__ nps,
    const int*   __restrict__ fnp,
    float4* __restrict__ bb, float2* __restrict__ cc) {
    int n = blockIdx.x * TPB + threadIdx.x;
    if (n >= NUM_NETS) return;
    int s = nps[n], e = nps[n + 1];
    float xmin = 1e30f, xmax = -1e30f, ymin = 1e30f, ymax = -1e30f;
    if (e - s == 4 && (s & 3) == 0) {
        int4 p4 = *(const int4*)(fnp + s);
        float x0 = pin_pos[p4.x], y0 = pin_pos[p4.x + NUM_PINS];
        float x1 = pin_pos[p4.y], y1 = pin_pos[p4.y + NUM_PINS];
        float x2 = pin_pos[p4.z], y2 = pin_pos[p4.z + NUM_PINS];
        float x3 = pin_pos[p4.w], y3 = pin_pos[p4.w + NUM_PINS];
        xmin = fminf(fminf(x0, x1), fminf(x2, x3));
        xmax = fmaxf(fmaxf(x0, x1), fmaxf(x2, x3));
        ymin = fminf(fminf(y0, y1), fminf(y2, y3));
        ymax = fmaxf(fmaxf(y0, y1), fmaxf(y2, y3));
    } else {
        for (int p = s; p < e; ++p) {
            int pin = fnp[p];
            float px = pin_pos[pin];
            float py = pin_pos[pin + NUM_PINS];
            xmin = fminf(xmin, px); xmax = fmaxf(xmax, px);
            ymin = fminf(ymin, py); ymax = fmaxf(ymax, py);
        }
    }
    float w  = (e > s) ? net_weights[n] : 0.f;
    float dx = xmax - xmin, dy = ymax - ymin;
    float cx = (e > s && dy > 0.f) ? w / dy : 0.f;
    float cy = (e > s && dx > 0.f) ? w / dx : 0.f;
    bb[n] = make_float4(xmin, xmax, ymin, ymax);
    cc[n] = make_float2(cx, cy);
}

// K2: per-block LDS-private 2D diff accumulation; two phases (x-map, y-map).
// LDS-atomic-pipe bound: ~3.2M ds_add_f32 total / gridDim blocks.
__global__ __launch_bounds__(TPB) void net_diff_kernel(
    const float4* __restrict__ bb,
    const float2* __restrict__ cc,
    float* __restrict__ Px, float* __restrict__ Py) {
    __shared__ float D[NCELL];   // 64 KB private diff array
    const int tid = threadIdx.x;
    const int gid = blockIdx.x * TPB + tid;
    const int T   = gridDim.x * TPB;

    float4* D4 = (float4*)D;
    for (int i = tid; i < NCELL / 4; i += TPB) D4[i] = make_float4(0,0,0,0);
    __syncthreads();

    for (int phase = 0; phase < 2; ++phase) {
        for (int n = gid; n < NUM_NETS; n += T) {
            float4 b  = bb[n];
            float2 c2 = cc[n];
            float c = (phase == 0) ? c2.x : c2.y;
            if (c == 0.f) continue;
            int ixs[4]; float vxs[4]; int iys[4]; float vys[4];
            int nx = second_diff(b.x, b.y, ixs, vxs);
            int ny = second_diff(b.z, b.w, iys, vys);
            for (int i = 0; i < nx; ++i) {
                int row = ixs[i];
                float cfi = c * vxs[i];
                if (cfi == 0.f || row >= NB) continue;
                for (int j = 0; j < ny; ++j) {
                    int col = iys[j];
                    float t = cfi * vys[j];
                    if (t == 0.f || col >= NB) continue;
                    atomicAdd(&D[row * NB + col], t);   // ds_add_f32, no return
                }
            }
        }
        __syncthreads();
        float4* P = (float4*)((phase == 0 ? Px : Py) + (size_t)blockIdx.x * NCELL);
        for (int i = tid; i < NCELL / 4; i += TPB) {
            P[i] = D4[i];
            D4[i] = make_float4(0,0,0,0);
        }
        __syncthreads();
    }
}

// K3: chunked partial reduction: R[chunk][map][cell] = sum over b-slice.
__global__ __launch_bounds__(256) void reduce_kernel(
    const float4* __restrict__ Px, const float4* __restrict__ Py,
    float4* __restrict__ R, int B) {
    constexpr int NC4 = NCELL / 4;
    int t = blockIdx.x * blockDim.x + threadIdx.x;   // 0 .. 2*NC4-1
    int chunk = blockIdx.y;
    if (t >= 2 * NC4) return;
    int m  = (t < NC4) ? 0 : 1;
    int c4 = t & (NC4 - 1);
    const float4* P = m ? Py : Px;
    int per = (B + NCHUNK - 1) / NCHUNK;
    int b0 = chunk * per;
    int b1 = min(b0 + per, B);
    float4 a0 = {0,0,0,0}, a1 = {0,0,0,0};
    int b = b0;
    for (; b + 1 < b1; b += 2) {
        float4 v0 = P[(size_t)b * NC4 + c4];
        float4 v1 = P[(size_t)(b + 1) * NC4 + c4];
        a0.x += v0.x; a0.y += v0.y; a0.z += v0.z; a0.w += v0.w;
        a1.x += v1.x; a1.y += v1.y; a1.z += v1.z; a1.w += v1.w;
    }
    for (; b < b1; ++b) {
        float4 v = P[(size_t)b * NC4 + c4];
        a0.x += v.x; a0.y += v.y; a0.z += v.z; a0.w += v.w;
    }
    float4 r;
    r.x = a0.x + a1.x; r.y = a0.y + a1.y; r.z = a0.z + a1.z; r.w = a0.w + a1.w;
    R[((size_t)(chunk * 2 + m)) * NC4 + c4] = r;
}

// K4: single-block fused finish: sum 4 chunks + x-prefix (phase A, via global
// Xp scratch), barrier, y-prefix + clip -> util (phase B). Block-internal
// barrier orders the global writes (same CU, L1-coherent).
__global__ __launch_bounds__(256) void finish_kernel(
    const float* __restrict__ R,
    float* __restrict__ Xp,      // [2][NCELL] scratch
    float* __restrict__ util) {
    int t = threadIdx.x;
    int m   = (t >= NB) ? 1 : 0;
    int col = t & (NB - 1);
    const float* Ra = R + (size_t)m * NCELL;
    float* O = Xp + (size_t)m * NCELL;
    float acc = 0.f;
    #pragma unroll 8
    for (int i = 0; i < NB; ++i) {
        int idx = i * NB + col;
        float v = Ra[idx] + Ra[2 * NCELL + idx] + Ra[4 * NCELL + idx]
                + Ra[6 * NCELL + idx];
        acc += v;
        O[idx] = acc;
    }
    __syncthreads();
    if (t < NB) {
        constexpr float invx = 1.f / (S * S * UNIT_H_CAP);
        constexpr float invy = 1.f / (S * S * UNIT_V_CAP);
        const float* Xx = Xp;
        const float* Xy = Xp + NCELL;
        float ax = 0.f, ay = 0.f;
        #pragma unroll 8
        for (int j = 0; j < NB; ++j) {
            int idx = t * NB + j;
            ax += Xx[idx];
            ay += Xy[idx];
            float u = fmaxf(ax * invx, ay * invy);
            util[idx] = fminf(fmaxf(u, 0.5f), 2.0f);
        }
    }
}

// K5: per-movable-node area = sum over <=3x3 bins of ox*util*oy
__global__ __launch_bounds__(256) void node_kernel(
    const float* __restrict__ pos,
    const float* __restrict__ nsx,
    const float* __restrict__ nsy,
    const float* __restrict__ util,
    float* __restrict__ out) {
    int m = blockIdx.x * blockDim.x + threadIdx.x;
    if (m >= NUM_MOVABLE) return;
    float x  = pos[m];
    float y  = pos[NUM_NODES + m];
    float xh = x + nsx[m];
    float yh = y + nsy[m];
    int ax = max(0,      (int)floorf(x  / S) - 1);
    int bx = min(NB - 1, (int)floorf(xh / S) + 1);
    int ay = max(0,      (int)floorf(y  / S) - 1);
    int by = min(NB - 1, (int)floorf(yh / S) + 1);
    float acc = 0.f;
    for (int i = ax; i <= bx; ++i) {
        float ov = fminf(edgef(i + 1), xh) - fmaxf(edgef(i), x);
        if (ov <= 0.f) continue;
        float inner = 0.f;
        for (int j = ay; j <= by; ++j) {
            float ovy = fminf(edgef(j + 1), yh) - fmaxf(edgef(j), y);
            if (ovy > 0.f) inner += ovy * util[i * NB + j];
        }
        acc += ov * inner;
    }
    out[m] = acc;
}

extern "C" void kernel_launch(void* const* d_in, const int* in_sizes, int n_in,
                              void* d_out, int out_size, void* d_ws, size_t ws_size,
                              hipStream_t stream) {
    const float* pos      = (const float*)d_in[0];
    const float* pin_pos  = (const float*)d_in[1];
    const float* nsx      = (const float*)d_in[2];
    const float* nsy      = (const float*)d_in[3];
    const float* nw       = (const float*)d_in[4];
    const int*   npstart  = (const int*)d_in[5];
    const int*   fnp      = (const int*)d_in[6];
    float*       out      = (float*)d_out;

    // ws layout (floats):
    // bb[4N] cc[2N] R[NCHUNK*2*NCELL] Xp[2*NCELL] util[NCELL] Px[B*NCELL] Py[B*NCELL]
    float* w    = (float*)d_ws;
    float4* bb  = (float4*)w;              w += 4 * NUM_NETS;
    float2* cc  = (float2*)w;              w += 2 * NUM_NETS;
    float* R    = w;                       w += NCHUNK * 2 * NCELL;
    float* Xp   = w;                       w += 2 * NCELL;
    float* util = w;                       w += NCELL;
    float* Px   = w;

    size_t fixed = (size_t)((w - (float*)d_ws)) * sizeof(float);
    int B = NDB;
    if (ws_size > fixed) {
        size_t fit = (ws_size - fixed) / ((size_t)2 * NCELL * sizeof(float));
        if ((size_t)B > fit) B = (int)fit;
    } else {
        B = 1;
    }
    if (B < 1) B = 1;
    float* Py = Px + (size_t)B * NCELL;

    bbox_kernel<<<(NUM_NETS + TPB - 1) / TPB, TPB, 0, stream>>>(
        pin_pos, nw, npstart, fnp, bb, cc);
    net_diff_kernel<<<B, TPB, 0, stream>>>(bb, cc, Px, Py);
    {
        dim3 g((2 * (NCELL / 4) + 255) / 256, NCHUNK);
        reduce_kernel<<<g, 256, 0, stream>>>(
            (const float4*)Px, (const float4*)Py, (float4*)R, B);
    }
    finish_kernel<<<1, 256, 0, stream>>>(R, Xp, util);
    node_kernel<<<(NUM_MOVABLE + 255) / 256, 256, 0, stream>>>(
        pos, nsx, nsy, util, out);
}

// Round 5
// 133.112 us; speedup vs baseline: 2.5215x; 1.1066x over previous
//
#include <hip/hip_runtime.h>

// Problem constants (from reference)
constexpr int   NB         = 128;          // bins per axis
constexpr int   NCELL      = NB * NB;      // 16384 cells = 64 KB fp32
constexpr float S          = 7.8125f;      // 1000/128, exact in fp32
constexpr int   NUM_NETS   = 100000;
constexpr int   NUM_NODES  = 200000;
constexpr int   NUM_MOVABLE= 180000;
constexpr int   NUM_PINS   = 400000;
constexpr float UNIT_H_CAP = 1.5f;
constexpr float UNIT_V_CAP = 1.4f;

#define TPB    512   // 256 blocks x 512 = 131072 threads >= 100000 nets: 1 net/thread
#define NDB    256   // one block per CU: LDS atomic pipe fully spread
#define NCHUNK 4     // b-parallelism in reduce

__device__ __forceinline__ float edgef(int t) { return (float)t * S; }

// exact bin index: edge(a) <= v < edge(a+1)
__device__ __forceinline__ int bin_of(float v) {
    int t = (int)floorf(v / S);
    while (edgef(t + 1) <= v) ++t;
    while (edgef(t)     >  v) --t;
    return t;
}

__device__ __forceinline__ float phi(int t, float lo, float hi) {
    return fminf(fmaxf(edgef(t), lo), hi);
}

// second difference of the clamp-ramp: <=4 nonzeros (indices >=128 are dropped
// by the caller; they never influence bins 0..127).
__device__ __forceinline__ int second_diff(float lo, float hi,
                                           int* idx, float* val) {
    int a = bin_of(lo);
    int b = bin_of(hi);
    int n = 0;
    idx[n] = a;
    val[n] = phi(a + 1, lo, hi) - 2.f * phi(a, lo, hi) + phi(a - 1, lo, hi);
    ++n;
    idx[n] = a + 1;
    val[n] = phi(a + 2, lo, hi) - 2.f * phi(a + 1, lo, hi) + phi(a, lo, hi);
    ++n;
    if (b > a + 1) {
        idx[n] = b;
        val[n] = phi(b + 1, lo, hi) - 2.f * phi(b, lo, hi) + phi(b - 1, lo, hi);
        ++n;
    }
    if (b > a) {
        idx[n] = b + 1;
        val[n] = phi(b + 2, lo, hi) - 2.f * phi(b + 1, lo, hi) + phi(b, lo, hi);
        ++n;
    }
    return n;
}

// K1: fused bbox gather + LDS-private 2D diff scatter (two phases: x-map,
// y-map). One net per thread; bbox/diffs persist in registers across phases.
__global__ __launch_bounds__(TPB) void net_diff_kernel(
    const float* __restrict__ pin_pos,
    const float* __restrict__ net_weights,
    const int*   __restrict__ nps,
    const int*   __restrict__ fnp,
    float* __restrict__ Px, float* __restrict__ Py) {
    __shared__ float D[NCELL];   // 64 KB private diff array
    const int tid = threadIdx.x;
    const int n   = blockIdx.x * TPB + tid;
    const bool have = (n < NUM_NETS);

    float4* D4 = (float4*)D;
    for (int i = tid; i < NCELL / 4; i += TPB) D4[i] = make_float4(0,0,0,0);

    float cx = 0.f, cy = 0.f;
    int ixs[4], iys[4];
    float vxs[4], vys[4];
    int nx = 0, ny = 0;

    if (have) {
        int s = nps[n], e = nps[n + 1];
        float xmin = 1e30f, xmax = -1e30f, ymin = 1e30f, ymax = -1e30f;
        if (e - s == 4 && (s & 3) == 0) {
            int4 p4 = *(const int4*)(fnp + s);
            float x0 = pin_pos[p4.x], y0 = pin_pos[p4.x + NUM_PINS];
            float x1 = pin_pos[p4.y], y1 = pin_pos[p4.y + NUM_PINS];
            float x2 = pin_pos[p4.z], y2 = pin_pos[p4.z + NUM_PINS];
            float x3 = pin_pos[p4.w], y3 = pin_pos[p4.w + NUM_PINS];
            xmin = fminf(fminf(x0, x1), fminf(x2, x3));
            xmax = fmaxf(fmaxf(x0, x1), fmaxf(x2, x3));
            ymin = fminf(fminf(y0, y1), fminf(y2, y3));
            ymax = fmaxf(fmaxf(y0, y1), fmaxf(y2, y3));
        } else {
            for (int p = s; p < e; ++p) {
                int pin = fnp[p];
                float px = pin_pos[pin];
                float py = pin_pos[pin + NUM_PINS];
                xmin = fminf(xmin, px); xmax = fmaxf(xmax, px);
                ymin = fminf(ymin, py); ymax = fmaxf(ymax, py);
            }
        }
        if (e > s) {
            float w  = net_weights[n];
            float dx = xmax - xmin, dy = ymax - ymin;
            cx = (dy > 0.f) ? w / dy : 0.f;
            cy = (dx > 0.f) ? w / dx : 0.f;
            if (cx != 0.f || cy != 0.f) {
                nx = second_diff(xmin, xmax, ixs, vxs);
                ny = second_diff(ymin, ymax, iys, vys);
            }
        }
    }
    __syncthreads();

    // phase 0: x-map (coefficient cx)
    if (have && cx != 0.f) {
        for (int i = 0; i < nx; ++i) {
            int row = ixs[i];
            float cfi = cx * vxs[i];
            if (cfi == 0.f || row >= NB) continue;
            for (int j = 0; j < ny; ++j) {
                int col = iys[j];
                float t = cfi * vys[j];
                if (t == 0.f || col >= NB) continue;
                atomicAdd(&D[row * NB + col], t);   // ds_add_f32, no return
            }
        }
    }
    __syncthreads();
    {
        float4* P = (float4*)(Px + (size_t)blockIdx.x * NCELL);
        for (int i = tid; i < NCELL / 4; i += TPB) {
            P[i] = D4[i];
            D4[i] = make_float4(0,0,0,0);
        }
    }
    __syncthreads();

    // phase 1: y-map (coefficient cy)
    if (have && cy != 0.f) {
        for (int i = 0; i < nx; ++i) {
            int row = ixs[i];
            float cfi = cy * vxs[i];
            if (cfi == 0.f || row >= NB) continue;
            for (int j = 0; j < ny; ++j) {
                int col = iys[j];
                float t = cfi * vys[j];
                if (t == 0.f || col >= NB) continue;
                atomicAdd(&D[row * NB + col], t);
            }
        }
    }
    __syncthreads();
    {
        float4* P = (float4*)(Py + (size_t)blockIdx.x * NCELL);
        for (int i = tid; i < NCELL / 4; i += TPB) P[i] = D4[i];
    }
}

// K2: chunked partial reduction: R[chunk][map][cell] = sum over b-slice.
__global__ __launch_bounds__(256) void reduce_kernel(
    const float4* __restrict__ Px, const float4* __restrict__ Py,
    float4* __restrict__ R, int B) {
    constexpr int NC4 = NCELL / 4;
    int t = blockIdx.x * blockDim.x + threadIdx.x;   // 0 .. 2*NC4-1
    int chunk = blockIdx.y;
    if (t >= 2 * NC4) return;
    int m  = (t < NC4) ? 0 : 1;
    int c4 = t & (NC4 - 1);
    const float4* P = m ? Py : Px;
    int per = (B + NCHUNK - 1) / NCHUNK;
    int b0 = chunk * per;
    int b1 = min(b0 + per, B);
    float4 a0 = {0,0,0,0}, a1 = {0,0,0,0};
    int b = b0;
    for (; b + 1 < b1; b += 2) {
        float4 v0 = P[(size_t)b * NC4 + c4];
        float4 v1 = P[(size_t)(b + 1) * NC4 + c4];
        a0.x += v0.x; a0.y += v0.y; a0.z += v0.z; a0.w += v0.w;
        a1.x += v1.x; a1.y += v1.y; a1.z += v1.z; a1.w += v1.w;
    }
    for (; b < b1; ++b) {
        float4 v = P[(size_t)b * NC4 + c4];
        a0.x += v.x; a0.y += v.y; a0.z += v.z; a0.w += v.w;
    }
    float4 r;
    r.x = a0.x + a1.x; r.y = a0.y + a1.y; r.z = a0.z + a1.z; r.w = a0.w + a1.w;
    R[((size_t)(chunk * 2 + m)) * NC4 + c4] = r;
}

// K3: single-block fused finish: sum chunks + x-prefix into global Xp scratch,
// barrier, y-prefix + clip -> util.
__global__ __launch_bounds__(256) void finish_kernel(
    const float* __restrict__ R,
    float* __restrict__ Xp,      // [2][NCELL] scratch
    float* __restrict__ util) {
    int t = threadIdx.x;
    int m   = (t >= NB) ? 1 : 0;
    int col = t & (NB - 1);
    const float* Ra = R + (size_t)m * NCELL;
    float* O = Xp + (size_t)m * NCELL;
    float acc = 0.f;
    #pragma unroll 8
    for (int i = 0; i < NB; ++i) {
        int idx = i * NB + col;
        float v = Ra[idx] + Ra[2 * NCELL + idx] + Ra[4 * NCELL + idx]
                + Ra[6 * NCELL + idx];
        acc += v;
        O[idx] = acc;
    }
    __syncthreads();
    if (t < NB) {
        constexpr float invx = 1.f / (S * S * UNIT_H_CAP);
        constexpr float invy = 1.f / (S * S * UNIT_V_CAP);
        const float* Xx = Xp;
        const float* Xy = Xp + NCELL;
        float ax = 0.f, ay = 0.f;
        #pragma unroll 8
        for (int j = 0; j < NB; ++j) {
            int idx = t * NB + j;
            ax += Xx[idx];
            ay += Xy[idx];
            float u = fmaxf(ax * invx, ay * invy);
            util[idx] = fminf(fmaxf(u, 0.5f), 2.0f);
        }
    }
}

// K4: per-movable-node area = sum over <=3x3 bins of ox*util*oy
__global__ __launch_bounds__(256) void node_kernel(
    const float* __restrict__ pos,
    const float* __restrict__ nsx,
    const float* __restrict__ nsy,
    const float* __restrict__ util,
    float* __restrict__ out) {
    int m = blockIdx.x * blockDim.x + threadIdx.x;
    if (m >= NUM_MOVABLE) return;
    float x  = pos[m];
    float y  = pos[NUM_NODES + m];
    float xh = x + nsx[m];
    float yh = y + nsy[m];
    int ax = max(0,      (int)floorf(x  / S) - 1);
    int bx = min(NB - 1, (int)floorf(xh / S) + 1);
    int ay = max(0,      (int)floorf(y  / S) - 1);
    int by = min(NB - 1, (int)floorf(yh / S) + 1);
    float acc = 0.f;
    for (int i = ax; i <= bx; ++i) {
        float ov = fminf(edgef(i + 1), xh) - fmaxf(edgef(i), x);
        if (ov <= 0.f) continue;
        float inner = 0.f;
        for (int j = ay; j <= by; ++j) {
            float ovy = fminf(edgef(j + 1), yh) - fmaxf(edgef(j), y);
            if (ovy > 0.f) inner += ovy * util[i * NB + j];
        }
        acc += ov * inner;
    }
    out[m] = acc;
}

extern "C" void kernel_launch(void* const* d_in, const int* in_sizes, int n_in,
                              void* d_out, int out_size, void* d_ws, size_t ws_size,
                              hipStream_t stream) {
    const float* pos      = (const float*)d_in[0];
    const float* pin_pos  = (const float*)d_in[1];
    const float* nsx      = (const float*)d_in[2];
    const float* nsy      = (const float*)d_in[3];
    const float* nw       = (const float*)d_in[4];
    const int*   npstart  = (const int*)d_in[5];
    const int*   fnp      = (const int*)d_in[6];
    float*       out      = (float*)d_out;

    // ws layout (floats): R[NCHUNK*2*NCELL] Xp[2*NCELL] util[NCELL]
    //                     Px[B*NCELL] Py[B*NCELL]
    float* w    = (float*)d_ws;
    float* R    = w;                       w += NCHUNK * 2 * NCELL;
    float* Xp   = w;                       w += 2 * NCELL;
    float* util = w;                       w += NCELL;
    float* Px   = w;

    size_t fixed = (size_t)(w - (float*)d_ws) * sizeof(float);
    int B = NDB;
    if (ws_size > fixed) {
        size_t fit = (ws_size - fixed) / ((size_t)2 * NCELL * sizeof(float));
        if ((size_t)B > fit) B = (int)fit;
    } else {
        B = 1;
    }
    if (B < 1) B = 1;
    float* Py = Px + (size_t)B * NCELL;

    net_diff_kernel<<<B, TPB, 0, stream>>>(pin_pos, nw, npstart, fnp, Px, Py);
    {
        dim3 g((2 * (NCELL / 4) + 255) / 256, NCHUNK);
        reduce_kernel<<<g, 256, 0, stream>>>(
            (const float4*)Px, (const float4*)Py, (float4*)R, B);
    }
    finish_kernel<<<1, 256, 0, stream>>>(R, Xp, util);
    node_kernel<<<(NUM_MOVABLE + 255) / 256, 256, 0, stream>>>(
        pos, nsx, nsy, util, out);
}